// Round 5
// baseline (231.582 us; speedup 1.0000x reference)
//
#include <hip/hip_runtime.h>

#define T_TOKENS 2048
#define N_EXPERTS 8
#define ROWS (T_TOKENS * 2)      // T * TOPK
#define I_DIM 2048
#define H_DIM 1024

#define M_TILE 128
#define N_TILE 128
#define BK 32
#define KSPLIT 2
#define KCHUNK (I_DIM / KSPLIT)  // 1024
#define NITER (KCHUNK / BK)      // 32

typedef __bf16 bf16x8 __attribute__((ext_vector_type(8)));
typedef __bf16 bf16x4 __attribute__((ext_vector_type(4)));
typedef float f32x4 __attribute__((ext_vector_type(4)));

__device__ inline void load_lds16(const void* g, void* l) {
    // global addr is PER-LANE; LDS side is wave-uniform base + lane*16
    __builtin_amdgcn_global_load_lds(
        (const __attribute__((address_space(1))) void*)g,
        (__attribute__((address_space(3))) void*)l, 16, 0, 0);
}

// Fused prep: (a) transpose+convert w [E][K][N] fp32 -> wT [E][N][K] bf16,
// (b) zero d_out, (c) zero cnt.
__global__ __launch_bounds__(256) void prep_kernel(
    const float* __restrict__ w, __bf16* __restrict__ wT,
    float* __restrict__ out, int* __restrict__ cnt) {
    const int bx = blockIdx.x;
    const int t = threadIdx.x;
    if (bx >= 4096) {
        int idx = (bx - 4096) * 256 + t;
        f32x4 z = (f32x4){0.f, 0.f, 0.f, 0.f};
        ((f32x4*)out)[2 * idx] = z;
        ((f32x4*)out)[2 * idx + 1] = z;
        if (bx == 4096 && t < N_EXPERTS) cnt[t] = 0;
        return;
    }
    __shared__ float tile[64 * 66];  // pitch 66 breaks bank conflicts
    const int e = bx >> 9;           // 512 blocks/expert = 32 ktiles * 16 ntiles
    const int k0 = ((bx >> 4) & 31) * 64;
    const int n0 = (bx & 15) * 64;
    const float* wsrc = w + (size_t)e * (I_DIM * H_DIM);
#pragma unroll
    for (int r = 0; r < 4; ++r) {
        int kl = (t >> 4) * 4 + r;
        int nl = (t & 15) * 4;
        f32x4 v = *(const f32x4*)(wsrc + (size_t)(k0 + kl) * H_DIM + n0 + nl);
        tile[kl * 66 + nl]     = v.x;
        tile[kl * 66 + nl + 1] = v.y;
        tile[kl * 66 + nl + 2] = v.z;
        tile[kl * 66 + nl + 3] = v.w;
    }
    __syncthreads();
    __bf16* wdst = wT + (size_t)e * (H_DIM * I_DIM);
#pragma unroll
    for (int r = 0; r < 4; ++r) {
        int nl = (t >> 4) * 4 + r;
        int klc = (t & 15) * 4;
        bf16x4 b = { (__bf16)tile[klc * 66 + nl],
                     (__bf16)tile[(klc + 1) * 66 + nl],
                     (__bf16)tile[(klc + 2) * 66 + nl],
                     (__bf16)tile[(klc + 3) * 66 + nl] };
        *(bf16x4*)(wdst + (size_t)(n0 + nl) * I_DIM + k0 + klc) = b;
    }
}

// One thread per token: softmax over 8 logits, top-2 (strict '>' keeps lower
// index on ties, matching jax.lax.top_k), append rows to per-expert lists.
__global__ void routing_kernel(const float* __restrict__ logits,
                               float* __restrict__ topk_w,
                               int* __restrict__ cnt,
                               int* __restrict__ rowlist) {
    int t = blockIdx.x * blockDim.x + threadIdx.x;
    if (t >= T_TOKENS) return;
    float l[8];
#pragma unroll
    for (int e = 0; e < 8; ++e) l[e] = logits[t * 8 + e];
    float mx = l[0];
#pragma unroll
    for (int e = 1; e < 8; ++e) mx = fmaxf(mx, l[e]);
    float s = 0.f;
#pragma unroll
    for (int e = 0; e < 8; ++e) { l[e] = expf(l[e] - mx); s += l[e]; }
    float inv = 1.f / s;
    float v0 = -1.f, v1 = -1.f; int i0 = 0, i1 = 0;
#pragma unroll
    for (int e = 0; e < 8; ++e) {
        float p = l[e] * inv;
        if (p > v0)      { v1 = v0; i1 = i0; v0 = p; i0 = e; }
        else if (p > v1) { v1 = p; i1 = e; }
    }
    topk_w[2 * t]     = v0;
    topk_w[2 * t + 1] = v1;
    int p0 = atomicAdd(&cnt[i0], 1); rowlist[i0 * ROWS + p0] = 2 * t;
    int p1 = atomicAdd(&cnt[i1], 1); rowlist[i1 * ROWS + p1] = 2 * t + 1;
}

// Grouped expert GEMM, 128x128 tile, bf16 MFMA 16x16x32.
// Both operands staged by global_load_lds DMA into fragment-ordered LDS
// (1KB lane-linear units -> conflict-free ds_read_b128). Double-buffered:
// DMA for tile k+1 issued right after the single per-iter barrier, so the
// whole compute phase of tile k hides the memory latency.
// A stays fp32 in LDS (per-lane gathered global addresses); cvt after ds_read.
__global__ __launch_bounds__(256, 2) void gemm_kernel(
    const float* __restrict__ x, const __bf16* __restrict__ wT,
    const int* __restrict__ cnt, const int* __restrict__ rowlist,
    const float* __restrict__ topk_w, float* __restrict__ out) {
    const int e = blockIdx.y;
    const int cnt_e = cnt[e];
    const int m0 = blockIdx.z * M_TILE;
    if (m0 >= cnt_e) return;
    const int ntile = blockIdx.x & 7;
    const int khalf = blockIdx.x >> 3;
    const int n0 = ntile * N_TILE;
    const int tid = threadIdx.x;
    const int lane = tid & 63;
    const int wave = tid >> 6;
    const int wm = wave & 1, wn = wave >> 1;

    // A: 8 units/buffer, unit u = 16 rows x 32 k fp32 (2KB = two DMA halves)
    //    layout: unit*512 + half*256 + (k4rel*16 + m)*4 floats
    // B: 8 units/buffer, unit u = 16 n x 32 k bf16 (1KB, one DMA, frag order)
    __shared__ float  As[2][M_TILE * BK];   // 2 x 16 KB
    __shared__ __bf16 Bs[2][N_TILE * BK];   // 2 x 8 KB

    const int* rl = rowlist + e * ROWS;
    const int m_lo = lane & 15, quad = lane >> 4;

    // per-wave staged units: {2*wave, 2*wave+1}
    int gm0 = m0 + 2 * wave * 16 + m_lo;
    int gm1 = gm0 + 16;
    int r0 = rl[gm0 < cnt_e ? gm0 : cnt_e - 1];
    int r1 = rl[gm1 < cnt_e ? gm1 : cnt_e - 1];
    const float* a_g0 = x + (size_t)r0 * I_DIM + quad * 4;  // + k0 (+16 for half 1)
    const float* a_g1 = x + (size_t)r1 * I_DIM + quad * 4;
    const __bf16* wTe = wT + (size_t)e * (H_DIM * I_DIM);
    const __bf16* b_g0 = wTe + (size_t)(n0 + 2 * wave * 16 + m_lo) * I_DIM + quad * 8;
    const __bf16* b_g1 = b_g0 + (size_t)16 * I_DIM;

    const int u0 = 2 * wave * 512, u1 = u0 + 512;

    f32x4 acc[4][4];
#pragma unroll
    for (int mt = 0; mt < 4; ++mt)
#pragma unroll
        for (int nt = 0; nt < 4; ++nt)
            acc[mt][nt] = (f32x4){0.f, 0.f, 0.f, 0.f};

    const int k_begin = khalf * KCHUNK;

    // prologue: DMA tile 0 into buffer 0
    {
        const int k0 = k_begin;
        load_lds16(b_g0 + k0, &Bs[0][u0]);
        load_lds16(b_g1 + k0, &Bs[0][u1]);
        load_lds16(a_g0 + k0,      &As[0][u0]);
        load_lds16(a_g0 + k0 + 16, &As[0][u0 + 256]);
        load_lds16(a_g1 + k0,      &As[0][u1]);
        load_lds16(a_g1 + k0 + 16, &As[0][u1 + 256]);
    }

    // A-frag read offset (floats): half*256 + k4rel*64 + m*4
    const int aoff = (quad >> 1) * 256 + ((2 * quad) & 3) * 64 + m_lo * 4;

    int buf = 0;
    for (int it = 0; it < NITER; ++it, buf ^= 1) {
        __syncthreads();   // drains tile-it DMA (issued a full iter ago); frees buf^1
        if (it + 1 < NITER) {
            const int kn = k_begin + (it + 1) * BK;
            load_lds16(b_g0 + kn, &Bs[buf ^ 1][u0]);
            load_lds16(b_g1 + kn, &Bs[buf ^ 1][u1]);
            load_lds16(a_g0 + kn,      &As[buf ^ 1][u0]);
            load_lds16(a_g0 + kn + 16, &As[buf ^ 1][u0 + 256]);
            load_lds16(a_g1 + kn,      &As[buf ^ 1][u1]);
            load_lds16(a_g1 + kn + 16, &As[buf ^ 1][u1 + 256]);
        }
        // B fragments: lane-linear, conflict-free
        bf16x8 bfr[4];
#pragma unroll
        for (int nt = 0; nt < 4; ++nt)
            bfr[nt] = *(const bf16x8*)&Bs[buf][(wn * 4 + nt) * 512 + lane * 8];
        // A fragments: two b128 fp32 reads + cvt
#pragma unroll
        for (int mt = 0; mt < 4; ++mt) {
            const float* ab = &As[buf][(wm * 4 + mt) * 512 + aoff];
            f32x4 lo = *(const f32x4*)ab;
            f32x4 hi = *(const f32x4*)(ab + 64);
            bf16x8 af = { (__bf16)lo.x, (__bf16)lo.y, (__bf16)lo.z, (__bf16)lo.w,
                          (__bf16)hi.x, (__bf16)hi.y, (__bf16)hi.z, (__bf16)hi.w };
#pragma unroll
            for (int nt = 0; nt < 4; ++nt)
                acc[mt][nt] = __builtin_amdgcn_mfma_f32_16x16x32_bf16(
                    af, bfr[nt], acc[mt][nt], 0, 0, 0);
        }
    }

    // epilogue: C/D col=lane&15, row=(lane>>4)*4+reg; scale by topk weight,
    // atomicAdd into out[token] (covers topk-sum and K-split sum)
#pragma unroll
    for (int mt = 0; mt < 4; ++mt) {
#pragma unroll
        for (int j = 0; j < 4; ++j) {
            int gm = m0 + wm * 64 + mt * 16 + quad * 4 + j;
            if (gm < cnt_e) {
                int row = rl[gm];
                float tw = topk_w[row];
                float* orow = out + (size_t)(row >> 1) * H_DIM + n0 + wn * 64 + m_lo;
#pragma unroll
                for (int nt = 0; nt < 4; ++nt)
                    atomicAdd(&orow[nt * 16], acc[mt][nt][j] * tw);
            }
        }
    }
}

extern "C" void kernel_launch(void* const* d_in, const int* in_sizes, int n_in,
                              void* d_out, int out_size, void* d_ws, size_t ws_size,
                              hipStream_t stream) {
    const float* x      = (const float*)d_in[0];  // [ROWS, I_DIM] fp32
    const float* w      = (const float*)d_in[1];  // [E, I_DIM, H_DIM] fp32
    const float* logits = (const float*)d_in[2];  // [T, E] fp32
    float* out = (float*)d_out;                   // [T, H_DIM] fp32

    char* ws = (char*)d_ws;
    float*  topk_w  = (float*)ws;                           // 4096 f32 (16 KB)
    int*    cnt     = (int*)(ws + 16384);                   // 8 int (padded)
    int*    rowlist = (int*)(ws + 16384 + 128);             // 8*4096 int (128 KB)
    __bf16* wT      = (__bf16*)(ws + 16384 + 128 + 131072); // [E][H][I] bf16 (32 MB)

    prep_kernel<<<4096 + 1024, 256, 0, stream>>>(w, wT, out, cnt);
    routing_kernel<<<T_TOKENS / 256, 256, 0, stream>>>(logits, topk_w, cnt, rowlist);
    // x = ntile+khalf (all active), y = expert, z = m-tile (early-exit tail)
    gemm_kernel<<<dim3((H_DIM / N_TILE) * KSPLIT, N_EXPERTS, ROWS / M_TILE), 256, 0, stream>>>(
        x, wT, cnt, rowlist, topk_w, out);
}

// Round 6
// 218.511 us; speedup vs baseline: 1.0598x; 1.0598x over previous
//
#include <hip/hip_runtime.h>

#define T_TOKENS 2048
#define N_EXPERTS 8
#define ROWS (T_TOKENS * 2)      // T * TOPK
#define I_DIM 2048
#define H_DIM 1024

#define M_TILE 64
#define N_TILE 128
#define BK 32
#define KSPLIT 2
#define KCHUNK (I_DIM / KSPLIT)  // 1024
#define NITER (KCHUNK / BK)      // 32

typedef __bf16 bf16x8 __attribute__((ext_vector_type(8)));
typedef __bf16 bf16x4 __attribute__((ext_vector_type(4)));
typedef float f32x4 __attribute__((ext_vector_type(4)));

__device__ inline void load_lds16(const void* g, void* l) {
    // lane i's 16B -> (wave-uniform) l + i*16 ; global side CONTIGUOUS 1KB here
    __builtin_amdgcn_global_load_lds(
        (const __attribute__((address_space(1))) void*)g,
        (__attribute__((address_space(3))) void*)l, 16, 0, 0);
}

// Packed-B layout: tile(e, nt, kb) = 8KB bf16 at ((e*8+nt)*64 + kb)*4096 elems.
// unit u (1KB) covers n in [nt*128+u*16, +16); elem (n,k): addr =
//   tile + u*512 + (quad*16 + (n&15))*8 + (k&7), quad=(k>>3)&3, kb=k>>5.
// This is exactly the gemm's LDS fragment order -> DMA reads are linear.
__global__ __launch_bounds__(256) void prep_kernel(
    const float* __restrict__ w, __bf16* __restrict__ bp,
    float* __restrict__ out) {
    const int bx = blockIdx.x;
    const int t = threadIdx.x;
    if (bx >= 4096) {
        // zero out: 1024 blocks * 256 thr * 8 floats = 2M floats
        int idx = (bx - 4096) * 256 + t;
        f32x4 z = (f32x4){0.f, 0.f, 0.f, 0.f};
        ((f32x4*)out)[2 * idx] = z;
        ((f32x4*)out)[2 * idx + 1] = z;
        return;
    }
    __shared__ float tile[64 * 66];  // pitch 66 breaks bank conflicts
    const int e = bx >> 9;           // 512 blocks/expert = 32 ktiles * 16 ntiles
    const int k0 = ((bx >> 4) & 31) * 64;
    const int n0 = (bx & 15) * 64;
    const float* wsrc = w + (size_t)e * (I_DIM * H_DIM);
#pragma unroll
    for (int r = 0; r < 4; ++r) {
        int kl = (t >> 4) * 4 + r;
        int nl = (t & 15) * 4;
        f32x4 v = *(const f32x4*)(wsrc + (size_t)(k0 + kl) * H_DIM + n0 + nl);
        tile[kl * 66 + nl]     = v.x;
        tile[kl * 66 + nl + 1] = v.y;
        tile[kl * 66 + nl + 2] = v.z;
        tile[kl * 66 + nl + 3] = v.w;
    }
    __syncthreads();
    const int nt = n0 >> 7;
    __bf16* base = bp + (size_t)(e * 8 + nt) * 64 * 4096;
#pragma unroll
    for (int r = 0; r < 4; ++r) {
        int nl = (t >> 4) * 4 + r;          // n within 64-tile
        int klc = (t & 15) * 4;             // k within 64-tile
        int n_rel = nl & 15;
        int u = ((n0 & 127) + nl) >> 4;
        int kb = (k0 + klc) >> 5;
        int quad = (klc >> 3) & 3;
        int j0 = klc & 7;                   // 0 or 4
        bf16x4 b = { (__bf16)tile[klc * 66 + nl],
                     (__bf16)tile[(klc + 1) * 66 + nl],
                     (__bf16)tile[(klc + 2) * 66 + nl],
                     (__bf16)tile[(klc + 3) * 66 + nl] };
        *(bf16x4*)&base[(size_t)kb * 4096 + u * 512 + (quad * 16 + n_rel) * 8 + j0] = b;
    }
}

// One thread per token: softmax over 8 logits, top-2 (strict '>' keeps lower
// index on ties, matching jax.lax.top_k), append rows to per-expert lists.
__global__ void routing_kernel(const float* __restrict__ logits,
                               float* __restrict__ topk_w,
                               int* __restrict__ cnt,
                               int* __restrict__ rowlist) {
    int t = blockIdx.x * blockDim.x + threadIdx.x;
    if (t >= T_TOKENS) return;
    float l[8];
#pragma unroll
    for (int e = 0; e < 8; ++e) l[e] = logits[t * 8 + e];
    float mx = l[0];
#pragma unroll
    for (int e = 1; e < 8; ++e) mx = fmaxf(mx, l[e]);
    float s = 0.f;
#pragma unroll
    for (int e = 0; e < 8; ++e) { l[e] = expf(l[e] - mx); s += l[e]; }
    float inv = 1.f / s;
    float v0 = -1.f, v1 = -1.f; int i0 = 0, i1 = 0;
#pragma unroll
    for (int e = 0; e < 8; ++e) {
        float p = l[e] * inv;
        if (p > v0)      { v1 = v0; i1 = i0; v0 = p; i0 = e; }
        else if (p > v1) { v1 = p; i1 = e; }
    }
    topk_w[2 * t]     = v0;
    topk_w[2 * t + 1] = v1;
    int p0 = atomicAdd(&cnt[i0], 1); rowlist[i0 * ROWS + p0] = 2 * t;
    int p1 = atomicAdd(&cnt[i1], 1); rowlist[i1 * ROWS + p1] = 2 * t + 1;
}

__device__ inline void write_a8(__bf16* dst, f32x4 a, f32x4 b) {
    bf16x8 v = { (__bf16)a.x, (__bf16)a.y, (__bf16)a.z, (__bf16)a.w,
                 (__bf16)b.x, (__bf16)b.y, (__bf16)b.z, (__bf16)b.w };
    *(bf16x8*)dst = v;
}

// Grouped expert GEMM, 64x128 tile, bf16 MFMA 16x16x32.
// B: contiguous 1KB global_load_lds from pre-packed tiles, double-buffered,
//    issued right after the single per-iter barrier (full compute phase to land).
// A: gathered f32x4 VGPR loads (depth-1 prefetch) + cvt + lane-linear ds_write_b128.
// All LDS accesses lane-linear -> conflict-free.
__global__ __launch_bounds__(256, 4) void gemm_kernel(
    const float* __restrict__ x, const __bf16* __restrict__ bp,
    const int* __restrict__ cnt, const int* __restrict__ rowlist,
    const float* __restrict__ topk_w, float* __restrict__ out) {
    const int e = blockIdx.y;
    const int cnt_e = cnt[e];
    const int m0 = blockIdx.z * M_TILE;
    if (m0 >= cnt_e) return;
    const int ntile = blockIdx.x & 7;
    const int khalf = blockIdx.x >> 3;
    const int n0 = ntile * N_TILE;
    const int tid = threadIdx.x;
    const int lane = tid & 63;
    const int wave = tid >> 6;
    const int wm = wave & 1, wn = wave >> 1;

    __shared__ __bf16 As[2][M_TILE * BK];   // 2 x 4 KB
    __shared__ __bf16 Bs[2][N_TILE * BK];   // 2 x 8 KB

    const int* rl = rowlist + e * ROWS;

    // A: thread t -> unit = wave, m_rel = t&15, quad = (t>>4)&3 (lane-linear write)
    const int m_rel = tid & 15;
    const int aq = (tid >> 4) & 3;
    const int arow = wave * 16 + m_rel;
    int gmA = m0 + arow;
    int gmc = gmA < cnt_e ? gmA : cnt_e - 1;   // clamped garbage dropped in epilogue
    const float* aptr = x + (size_t)rl[gmc] * I_DIM + aq * 8;
    const int as_off = wave * 512 + (aq * 16 + m_rel) * 8;  // == wave*512 + (lane)*8

    // B: wave stages units {2w, 2w+1}; per-lane src = base + it*4096 + lane*8 elems
    const __bf16* bbase = bp + ((size_t)(e * 8 + ntile) * 64 + khalf * 32) * 4096
                             + 2 * wave * 512 + lane * 8;
    const int bdst = 2 * wave * 512;

    f32x4 acc[2][4];
#pragma unroll
    for (int mt = 0; mt < 2; ++mt)
#pragma unroll
        for (int nt = 0; nt < 4; ++nt)
            acc[mt][nt] = (f32x4){0.f, 0.f, 0.f, 0.f};

    const int k_begin = khalf * KCHUNK;

    // prologue: tile 0 -> buf 0; A regs for tile 1
    f32x4 va0 = *(const f32x4*)(aptr + k_begin);
    f32x4 va1 = *(const f32x4*)(aptr + k_begin + 4);
    load_lds16(bbase,       &Bs[0][bdst]);
    load_lds16(bbase + 512, &Bs[0][bdst + 512]);
    f32x4 wa0 = *(const f32x4*)(aptr + k_begin + BK);
    f32x4 wa1 = *(const f32x4*)(aptr + k_begin + BK + 4);
    write_a8(&As[0][as_off], va0, va1);

    for (int it = 0; it < NITER; ++it) {
        const int buf = it & 1;
        __syncthreads();   // tile-it DMA + ds_write visible; buf^1 free
        if (it + 1 < NITER) {
            const __bf16* bs = bbase + (size_t)(it + 1) * 4096;
            load_lds16(bs,       &Bs[buf ^ 1][bdst]);
            load_lds16(bs + 512, &Bs[buf ^ 1][bdst + 512]);
            write_a8(&As[buf ^ 1][as_off], wa0, wa1);   // regs loaded 1 iter ago
            if (it + 2 < NITER) {
                wa0 = *(const f32x4*)(aptr + k_begin + (it + 2) * BK);
                wa1 = *(const f32x4*)(aptr + k_begin + (it + 2) * BK + 4);
            }
        }
        // fragments (lane-linear, conflict-free) + MFMA
        bf16x8 bfr[4];
#pragma unroll
        for (int nt = 0; nt < 4; ++nt)
            bfr[nt] = *(const bf16x8*)&Bs[buf][(wn * 4 + nt) * 512 + lane * 8];
        bf16x8 af[2];
#pragma unroll
        for (int mt = 0; mt < 2; ++mt)
            af[mt] = *(const bf16x8*)&As[buf][(wm * 2 + mt) * 512 + lane * 8];
#pragma unroll
        for (int mt = 0; mt < 2; ++mt)
#pragma unroll
            for (int nt = 0; nt < 4; ++nt)
                acc[mt][nt] = __builtin_amdgcn_mfma_f32_16x16x32_bf16(
                    af[mt], bfr[nt], acc[mt][nt], 0, 0, 0);
    }

    // epilogue: C/D col=lane&15, row=(lane>>4)*4+reg; scale by topk weight,
    // atomicAdd into out[token] (covers topk-sum and K-split sum)
    const int lq = lane >> 4, ln = lane & 15;
#pragma unroll
    for (int mt = 0; mt < 2; ++mt) {
#pragma unroll
        for (int j = 0; j < 4; ++j) {
            int gm = m0 + wm * 32 + mt * 16 + lq * 4 + j;
            if (gm < cnt_e) {
                int row = rl[gm];
                float tw = topk_w[row];
                float* orow = out + (size_t)(row >> 1) * H_DIM + n0 + wn * 64 + ln;
#pragma unroll
                for (int nt = 0; nt < 4; ++nt)
                    atomicAdd(&orow[nt * 16], acc[mt][nt][j] * tw);
            }
        }
    }
}

extern "C" void kernel_launch(void* const* d_in, const int* in_sizes, int n_in,
                              void* d_out, int out_size, void* d_ws, size_t ws_size,
                              hipStream_t stream) {
    const float* x      = (const float*)d_in[0];  // [ROWS, I_DIM] fp32
    const float* w      = (const float*)d_in[1];  // [E, I_DIM, H_DIM] fp32
    const float* logits = (const float*)d_in[2];  // [T, E] fp32
    float* out = (float*)d_out;                   // [T, H_DIM] fp32

    char* ws = (char*)d_ws;
    float*  topk_w  = (float*)ws;                           // 4096 f32 (16 KB)
    int*    cnt     = (int*)(ws + 16384);                   // 8 int (padded)
    int*    rowlist = (int*)(ws + 16384 + 128);             // 8*4096 int (128 KB)
    __bf16* bp      = (__bf16*)(ws + 16384 + 128 + 131072); // packed B tiles (32 MB)

    hipMemsetAsync(cnt, 0, N_EXPERTS * sizeof(int), stream);
    routing_kernel<<<T_TOKENS / 256, 256, 0, stream>>>(logits, topk_w, cnt, rowlist);
    prep_kernel<<<4096 + 1024, 256, 0, stream>>>(w, bp, out);
    // x = ntile+khalf (all active), y = expert, z = m-tile (early-exit tail)
    gemm_kernel<<<dim3((H_DIM / N_TILE) * KSPLIT, N_EXPERTS, ROWS / M_TILE), 256, 0, stream>>>(
        x, bp, cnt, rowlist, topk_w, out);
}